// Round 4
// baseline (3541.252 us; speedup 1.0000x reference)
//
#include <hip/hip_runtime.h>
#include <math.h>

#define BB 4
#define NF 128
#define CS 192
#define CH 96
#define H1 64
#define W1 64
#define H2 128
#define W2 128
#define P1 (H1*W1)
#define P2 (H2*W2)
#define EPSV 1e-5f
#define DTV 0.25f

typedef __attribute__((ext_vector_type(8))) short short8;
typedef __attribute__((ext_vector_type(4))) float f32x4;

__device__ __forceinline__ float softplus_f(float x) {
    return fmaxf(x, 0.0f) + log1pf(expf(-fabsf(x)));
}
__device__ __forceinline__ unsigned f2bf(float f) {
    unsigned u = __float_as_uint(f);
    return (u + 0x7FFFu + ((u >> 16) & 1u)) >> 16;   // RNE to bf16
}
__device__ __forceinline__ float bf2f(short s) {
    return __uint_as_float(((unsigned)(unsigned short)s) << 16);
}

__global__ __launch_bounds__(256) void zero_kernel(float* __restrict__ p, int n) {
    int i = blockIdx.x * 256 + threadIdx.x;
    if (i < n) p[i] = 0.f;
}

// per-(b,c) raw (sum,sumsq) over HW for fp32 NCHW input x. grid = B*C.
__global__ __launch_bounds__(256) void meanvar_raw_kernel(const float* __restrict__ x,
                                                          float* __restrict__ mv, int HW) {
    int bc = blockIdx.x;
    const float* p = x + (size_t)bc * HW;
    float s = 0.f, s2 = 0.f;
    for (int i = threadIdx.x; i < HW; i += 256) {
        float v = p[i];
        s += v; s2 += v * v;
    }
    __shared__ float sh[512];
    sh[threadIdx.x] = s; sh[256 + threadIdx.x] = s2;
    __syncthreads();
    for (int o = 128; o > 0; o >>= 1) {
        if (threadIdx.x < o) {
            sh[threadIdx.x] += sh[threadIdx.x + o];
            sh[256 + threadIdx.x] += sh[256 + threadIdx.x + o];
        }
        __syncthreads();
    }
    if (threadIdx.x == 0) {
        mv[2 * bc]     = sh[0];
        mv[2 * bc + 1] = sh[256];
    }
}

// raw (sum,sumsq) per (b,c) for bf16 NHWC tensor with C=192. grid (64, B).
__global__ __launch_bounds__(256) void stats_nhwc_kernel(const short* __restrict__ t,
                                                         float* __restrict__ osum) {
    const int tid = threadIdx.x;
    const int k = tid % 24;          // int4-chunk within the 192-ch row
    const int ps = tid / 24;         // 0..9 active (tid < 240)
    const int px0 = blockIdx.x * (P2 / 64);
    const int b = blockIdx.y;
    float s1[8], s2[8];
#pragma unroll
    for (int i = 0; i < 8; i++) { s1[i] = 0.f; s2[i] = 0.f; }
    if (tid < 240) {
        for (int px = px0 + ps; px < px0 + P2 / 64; px += 10) {
            short8 v = *(const short8*)(t + ((size_t)b * P2 + px) * 192 + k * 8);
#pragma unroll
            for (int i = 0; i < 8; i++) {
                float f = bf2f(v[i]);
                s1[i] += f; s2[i] += f * f;
            }
        }
    }
    __shared__ float red[240][16];
    if (tid < 240) {
#pragma unroll
        for (int i = 0; i < 8; i++) { red[tid][i] = s1[i]; red[tid][8 + i] = s2[i]; }
    }
    __syncthreads();
    for (int idx = tid; idx < 384; idx += 256) {
        int kk = idx / 16, e = idx % 16;
        float a = 0.f;
#pragma unroll
        for (int p = 0; p < 10; p++) a += red[p * 24 + kk][e];
        int ch = kk * 8 + (e & 7);
        atomicAdd(&osum[((size_t)b * CS + ch) * 2 + (e >> 3)], a);
    }
}

// repack w[co][ci][3][3] fp32 -> wq[tap][co][ci] bf16
__global__ __launch_bounds__(256) void repack_w_kernel(const float* __restrict__ w,
                                                       short* __restrict__ wq,
                                                       int Cout, int Cin) {
    int idx = blockIdx.x * 256 + threadIdx.x;
    int total = Cout * Cin * 9;
    if (idx >= total) return;
    int tap = idx % 9;
    int t = idx / 9;
    int ci = t % Cin, co = t / Cin;
    wq[((size_t)tap * Cout + co) * Cin + ci] = (short)f2bf(w[idx]);
}

__global__ __launch_bounds__(256) void repack_w1_kernel(const float* __restrict__ w,
                                                        short* __restrict__ wq, int n) {
    int i = blockIdx.x * 256 + threadIdx.x;
    if (i < n) wq[i] = (short)f2bf(w[i]);
}

// x fp32 NCHW (B,128,P1) -> bf16 NHWC [b][px][128]. grid (P1/64, B).
__global__ __launch_bounds__(256) void xcvt_kernel(const float* __restrict__ x,
                                                   short* __restrict__ xbf) {
    int pxl = threadIdx.x & 63, cq = threadIdx.x >> 6;
    int px = blockIdx.x * 64 + pxl;
    int b = blockIdx.y;
    short* orow = xbf + ((size_t)b * P1 + px) * NF;
#pragma unroll
    for (int j = 0; j < 16; j++) {
        int c0 = cq * 32 + j * 2;
        float a = x[((size_t)(b * NF + c0)) * P1 + px];
        float c = x[((size_t)(b * NF + c0 + 1)) * P1 + px];
        *(int*)(orow + c0) = (int)(f2bf(a) | (f2bf(c) << 16));
    }
}

// 3x3 SAME conv: bf16 NHWC input + instance-norm at staging (stats from raw sums),
// register-prefetch pipelined staging, MFMA 16x16x32 bf16, softplus+bias epilogue.
// Output: fp32 NCHW (OUTBF=false) or bf16 NHWC (OUTBF=true). Optional fused out sums.
// grid (W/16, H/8, B*coblk), block 256.
template<int NCG, bool OUTBF, bool SUMS>
__global__ __launch_bounds__(256) void conv3x3_mfma(
    const short* __restrict__ in, const float* __restrict__ mvsums,
    const short* __restrict__ wq, const float* __restrict__ bias,
    float* __restrict__ outf, short* __restrict__ outbf, float* __restrict__ osum,
    int Cin, int CoutT, int H, int W, int outC, int outCoff, int coblk)
{
    __shared__ short xt[180 * 40];     // 18x10 halo px, 80B/px (32 bf16 + pad)
    __shared__ float mvm[CS], mvr[CS];
    __shared__ float shs[2 * CH];
    const int tid = threadIdx.x;
    const int wave = tid >> 6, lane = tid & 63;
    const int lx = lane & 15, q = lane >> 4;
    const int x0 = blockIdx.x * 16, y0 = blockIdx.y * 8;
    const int b = blockIdx.z / coblk;
    const int co_base = (blockIdx.z % coblk) * (NCG * 16);
    const int HWp = H * W;
    const short* inb = in + (size_t)b * HWp * Cin;

    const float invHW = 1.0f / (float)HWp;
    for (int c = tid; c < Cin; c += 256) {
        float s  = mvsums[(b * Cin + c) * 2];
        float s2 = mvsums[(b * Cin + c) * 2 + 1];
        float m  = s * invHW;
        float var = fmaxf(s2 * invHW - m * m, 0.f);
        mvm[c] = m;
        mvr[c] = rsqrtf(var + EPSV);
    }
    if (SUMS) for (int c = tid; c < 2 * CH; c += 256) shs[c] = 0.f;
    __syncthreads();

    // staging jobs: j in [0,720): part=j&3 (8-ch group), px=j>>2 (halo index)
    int jl[3], jg[3], jc[3]; bool jok[3]; int nj = 0;
#pragma unroll
    for (int k = 0; k < 3; k++) {
        int j = tid + 256 * k;
        if (j < 720) {
            int part = j & 3, px = j >> 2;
            int yy = px / 18, xx = px - yy * 18;
            int gy = y0 + yy - 1, gx = x0 + xx - 1;
            bool ok = (gy >= 0 && gy < H && gx >= 0 && gx < W);
            jl[nj] = px * 40 + part * 8;
            jg[nj] = ok ? ((gy * W + gx) * Cin + part * 8) : 0;
            jc[nj] = part * 8;
            jok[nj] = ok;
            nj++;
        }
    }

    f32x4 acc[2][NCG];
#pragma unroll
    for (int rr = 0; rr < 2; rr++)
#pragma unroll
        for (int cg = 0; cg < NCG; cg++) acc[rr][cg] = (f32x4)(0.f);

    const int NIT = Cin >> 5;
    short8 pf[3];
#pragma unroll
    for (int k = 0; k < 3; k++)
        if (k < nj && jok[k]) pf[k] = *(const short8*)(inb + jg[k]);

    for (int it = 0; it < NIT; it++) {
        const int ci0 = it << 5;
        if (it > 0) __syncthreads();
        // normalize + pack prefetched data into LDS
#pragma unroll
        for (int k = 0; k < 3; k++) {
            if (k < nj) {
                int4 wv = make_int4(0, 0, 0, 0);
                if (jok[k]) {
                    int cb = ci0 + jc[k];
                    float4 m0 = *(const float4*)&mvm[cb];
                    float4 m1 = *(const float4*)&mvm[cb + 4];
                    float4 r0 = *(const float4*)&mvr[cb];
                    float4 r1 = *(const float4*)&mvr[cb + 4];
                    short8 v = pf[k];
                    float o0 = (bf2f(v[0]) - m0.x) * r0.x;
                    float o1 = (bf2f(v[1]) - m0.y) * r0.y;
                    float o2 = (bf2f(v[2]) - m0.z) * r0.z;
                    float o3 = (bf2f(v[3]) - m0.w) * r0.w;
                    float o4 = (bf2f(v[4]) - m1.x) * r1.x;
                    float o5 = (bf2f(v[5]) - m1.y) * r1.y;
                    float o6 = (bf2f(v[6]) - m1.z) * r1.z;
                    float o7 = (bf2f(v[7]) - m1.w) * r1.w;
                    wv.x = (int)(f2bf(o0) | (f2bf(o1) << 16));
                    wv.y = (int)(f2bf(o2) | (f2bf(o3) << 16));
                    wv.z = (int)(f2bf(o4) | (f2bf(o5) << 16));
                    wv.w = (int)(f2bf(o6) | (f2bf(o7) << 16));
                }
                *(int4*)(&xt[jl[k]]) = wv;
            }
        }
        __syncthreads();
        // prefetch next chunk (overlaps with MFMA below)
        if (it + 1 < NIT) {
            const int cn = (it + 1) << 5;
#pragma unroll
            for (int k = 0; k < 3; k++)
                if (k < nj && jok[k]) pf[k] = *(const short8*)(inb + jg[k] + cn);
        }
        const short* wl = wq + (size_t)(co_base + lx) * Cin + ci0 + q * 8;
#pragma unroll
        for (int tap = 0; tap < 9; tap++) {
            const int dy = tap / 3, dx = tap % 3;
            short8 a[NCG];
#pragma unroll
            for (int cg = 0; cg < NCG; cg++)
                a[cg] = *(const short8*)(wl + ((size_t)tap * CoutT + cg * 16) * Cin);
#pragma unroll
            for (int rr = 0; rr < 2; rr++) {
                int row = wave * 2 + rr;
                short8 bfr = *(const short8*)(&xt[((row + dy) * 18 + lx + dx) * 40 + q * 8]);
#pragma unroll
                for (int cg = 0; cg < NCG; cg++)
                    acc[rr][cg] = __builtin_amdgcn_mfma_f32_16x16x32_bf16(
                        a[cg], bfr, acc[rr][cg], 0, 0, 0);
            }
        }
    }

    float s1l[NCG][4], s2l[NCG][4];
    if (SUMS) {
#pragma unroll
        for (int cg = 0; cg < NCG; cg++)
#pragma unroll
            for (int r = 0; r < 4; r++) { s1l[cg][r] = 0.f; s2l[cg][r] = 0.f; }
    }
#pragma unroll
    for (int rr = 0; rr < 2; rr++) {
        int y = y0 + wave * 2 + rr;
#pragma unroll
        for (int cg = 0; cg < NCG; cg++) {
            float v[4];
#pragma unroll
            for (int r = 0; r < 4; r++) {
                int co = cg * 16 + q * 4 + r;
                v[r] = softplus_f(acc[rr][cg][r] + bias[co_base + co]);
                if (SUMS) { s1l[cg][r] += v[r]; s2l[cg][r] += v[r] * v[r]; }
            }
            if (OUTBF) {
                short* orow = outbf + ((size_t)b * HWp + y * W + x0 + lx) * outC
                              + outCoff + co_base + cg * 16 + q * 4;
                *(int*)orow       = (int)(f2bf(v[0]) | (f2bf(v[1]) << 16));
                *(int*)(orow + 2) = (int)(f2bf(v[2]) | (f2bf(v[3]) << 16));
            } else {
                float* ob = outf + ((size_t)b * outC + outCoff + co_base) * HWp
                            + y * W + x0 + lx;
#pragma unroll
                for (int r = 0; r < 4; r++)
                    ob[(size_t)(cg * 16 + q * 4 + r) * HWp] = v[r];
            }
        }
    }
    if (SUMS) {
#pragma unroll
        for (int cg = 0; cg < NCG; cg++)
#pragma unroll
            for (int r = 0; r < 4; r++) {
                float a1 = s1l[cg][r], a2 = s2l[cg][r];
#pragma unroll
                for (int mask = 1; mask < 16; mask <<= 1) {
                    a1 += __shfl_xor(a1, mask);
                    a2 += __shfl_xor(a2, mask);
                }
                if (lx == 0) {
                    int co = cg * 16 + q * 4 + r;
                    atomicAdd(&shs[2 * co], a1);
                    atomicAdd(&shs[2 * co + 1], a2);
                }
            }
        __syncthreads();
        for (int c = tid; c < 2 * NCG * 16; c += 256)
            atomicAdd(&osum[(size_t)b * 2 * NCG * 16 + c], shs[c]);
    }
}

// bilinear 2x upsample of concat(x,v0) + skip concat -> YCAT bf16 NHWC [b][px][384].
// grid (P2/64, B); thread (px-lane, ch-quarter).
__global__ __launch_bounds__(256) void upsample_kernel(
    const float* __restrict__ x, const float* __restrict__ v0,
    const float* __restrict__ skip, short* __restrict__ ycat)
{
    int pxl = threadIdx.x & 63, cq = threadIdx.x >> 6;
    int px = blockIdx.x * 64 + pxl;
    int b = blockIdx.y;
    int ox = px & 127, oy = px >> 7;
    int my = oy >> 1, mx = ox >> 1;
    int iy0 = (oy & 1) ? my : my - 1;
    float wy0 = (oy & 1) ? 0.75f : 0.25f;
    int ix0 = (ox & 1) ? mx : mx - 1;
    float wx0 = (ox & 1) ? 0.75f : 0.25f;
    int iy1 = min(iy0 + 1, H1 - 1); iy0 = max(iy0, 0);
    int ix1 = min(ix0 + 1, W1 - 1); ix0 = max(ix0, 0);
    float wy1 = 1.f - wy0, wx1 = 1.f - wx0;
    float w00 = wy0 * wx0, w01 = wy0 * wx1, w10 = wy1 * wx0, w11 = wy1 * wx1;
    int o00 = iy0 * W1 + ix0, o01 = iy0 * W1 + ix1;
    int o10 = iy1 * W1 + ix0, o11 = iy1 * W1 + ix1;
    short* orow = ycat + ((size_t)b * P2 + px) * 384;
#pragma unroll 4
    for (int j = 0; j < 48; j++) {
        int c0 = cq * 96 + j * 2;
        float v[2];
#pragma unroll
        for (int i = 0; i < 2; i++) {
            int c = c0 + i;
            if (c < 256) {
                const float* src = (c < 128) ? x + ((size_t)(b * NF + c)) * P1
                                             : v0 + ((size_t)(b * NF + c - 128)) * P1;
                v[i] = w00 * src[o00] + w01 * src[o01] + w10 * src[o10] + w11 * src[o11];
            } else {
                v[i] = skip[((size_t)(b * NF + c - 256)) * P2 + px];
            }
        }
        *(int*)(orow + c0) = (int)(f2bf(v[0]) | (f2bf(v[1]) << 16));
    }
}

// 1x1 conv 384->192: YCAT bf16 NHWC in, MFMA, softplus; writes S fp32 NCHW +
// Sbf bf16 NHWC + fused channel sums. grid (P2/64, B).
__global__ __launch_bounds__(256) void conv1x1_mfma(
    const short* __restrict__ ycat, const short* __restrict__ wq,
    const float* __restrict__ bias, float* __restrict__ out,
    short* __restrict__ sbf, float* __restrict__ osum)
{
    __shared__ short xs[64 * 40];
    const int tid = threadIdx.x;
    const int wave = tid >> 6, lane = tid & 63;
    const int lx = lane & 15, q = lane >> 4;
    const int p0 = blockIdx.x * 64;
    const int b = blockIdx.y;
    const int spx = tid >> 2, spart = tid & 3;
    const size_t gofs = ((size_t)b * P2 + p0 + spx) * 384 + spart * 8;
    const int ldso = spx * 40 + spart * 8;

    f32x4 acc[3][4];
#pragma unroll
    for (int cg = 0; cg < 3; cg++)
#pragma unroll
        for (int pg = 0; pg < 4; pg++) acc[cg][pg] = (f32x4)(0.f);

    short8 pf = *(const short8*)(ycat + gofs);
    for (int it = 0; it < 12; it++) {
        if (it > 0) __syncthreads();
        *(short8*)(&xs[ldso]) = pf;
        __syncthreads();
        if (it < 11) pf = *(const short8*)(ycat + gofs + (it + 1) * 32);
        const short* wl = wq + (size_t)(wave * 48 + lx) * 384 + it * 32 + q * 8;
        short8 a[3];
#pragma unroll
        for (int cg = 0; cg < 3; cg++)
            a[cg] = *(const short8*)(wl + (size_t)cg * 16 * 384);
#pragma unroll
        for (int pg = 0; pg < 4; pg++) {
            short8 bfr = *(const short8*)(&xs[(pg * 16 + lx) * 40 + q * 8]);
#pragma unroll
            for (int cg = 0; cg < 3; cg++)
                acc[cg][pg] = __builtin_amdgcn_mfma_f32_16x16x32_bf16(
                    a[cg], bfr, acc[cg][pg], 0, 0, 0);
        }
    }

    float s1a[3][4], s2a[3][4];
#pragma unroll
    for (int cg = 0; cg < 3; cg++)
#pragma unroll
        for (int r = 0; r < 4; r++) { s1a[cg][r] = 0.f; s2a[cg][r] = 0.f; }
#pragma unroll
    for (int cg = 0; cg < 3; cg++) {
        int co0 = wave * 48 + cg * 16 + q * 4;
#pragma unroll
        for (int pg = 0; pg < 4; pg++) {
            int px = p0 + pg * 16 + lx;
            float v[4];
#pragma unroll
            for (int r = 0; r < 4; r++) {
                v[r] = softplus_f(acc[cg][pg][r] + bias[co0 + r]);
                out[((size_t)(b * CS + co0 + r)) * P2 + px] = v[r];
                s1a[cg][r] += v[r]; s2a[cg][r] += v[r] * v[r];
            }
            short* orow = sbf + ((size_t)b * P2 + px) * 192 + co0;
            *(int*)orow       = (int)(f2bf(v[0]) | (f2bf(v[1]) << 16));
            *(int*)(orow + 2) = (int)(f2bf(v[2]) | (f2bf(v[3]) << 16));
        }
    }
#pragma unroll
    for (int cg = 0; cg < 3; cg++)
#pragma unroll
        for (int r = 0; r < 4; r++) {
            float a1 = s1a[cg][r], a2 = s2a[cg][r];
#pragma unroll
            for (int mask = 1; mask < 16; mask <<= 1) {
                a1 += __shfl_xor(a1, mask);
                a2 += __shfl_xor(a2, mask);
            }
            if (lx == 0) {
                int co = wave * 48 + cg * 16 + q * 4 + r;
                atomicAdd(&osum[((size_t)b * CS + co) * 2], a1);
                atomicAdd(&osum[((size_t)b * CS + co) * 2 + 1], a2);
            }
        }
}

// T[a] = S_a + ca1*S_b + ca2*Gx ; T[b] = S_b + cb*Gp ; T bf16 NHWC.
// grid (P2/64, B); thread (px-lane, ch-quarter of 24).
__global__ __launch_bounds__(256) void combine_kernel(
    const float* __restrict__ S, const float* __restrict__ Gx,
    const float* __restrict__ Gp, short* __restrict__ T,
    float ca1, float ca2, float cb)
{
    int pxl = threadIdx.x & 63, cq = threadIdx.x >> 6;
    int px = blockIdx.x * 64 + pxl;
    int b = blockIdx.y;
    short* orow = T + ((size_t)b * P2 + px) * 192;
#pragma unroll 3
    for (int j = 0; j < 12; j++) {
        int c0 = cq * 24 + j * 2;
        size_t ia = ((size_t)(b * CS + c0)) * P2 + px;
        size_t ib = ia + (size_t)CH * P2;
        size_t ig = ((size_t)(b * CH + c0)) * P2 + px;
        float sa0 = S[ia], sa1 = S[ia + P2];
        float sb0 = S[ib], sb1 = S[ib + P2];
        float gx0 = Gx[ig], gx1 = Gx[ig + P2];
        float gp0 = Gp[ig], gp1 = Gp[ig + P2];
        float ta0 = sa0 + ca1 * sb0 + ca2 * gx0;
        float ta1 = sa1 + ca1 * sb1 + ca2 * gx1;
        float tb0 = sb0 + cb * gp0;
        float tb1 = sb1 + cb * gp1;
        *(int*)(orow + c0)      = (int)(f2bf(ta0) | (f2bf(ta1) << 16));
        *(int*)(orow + 96 + c0) = (int)(f2bf(tb0) | (f2bf(tb1) << 16));
    }
}

// S_a += h*S_b + h^2/6*(g1+g2+g3); S_b += h/6*(g1+2g2+2g3+g4); optional Sbf bf16 NHWC.
template<bool SBF>
__global__ __launch_bounds__(256) void final_kernel(
    float* __restrict__ S, const float* __restrict__ G1, const float* __restrict__ G2,
    const float* __restrict__ G3, const float* __restrict__ G4, short* __restrict__ sbf)
{
    int pxl = threadIdx.x & 63, cq = threadIdx.x >> 6;
    int px = blockIdx.x * 64 + pxl;
    int b = blockIdx.y;
    const float cA = DTV * DTV / 6.0f, cB = DTV / 6.0f;
    short* orow = sbf + ((size_t)b * P2 + px) * 192;
#pragma unroll 3
    for (int j = 0; j < 12; j++) {
        int c0 = cq * 24 + j * 2;
        size_t ia = ((size_t)(b * CS + c0)) * P2 + px;
        size_t ib = ia + (size_t)CH * P2;
        size_t ig = ((size_t)(b * CH + c0)) * P2 + px;
        float sa0 = S[ia], sa1 = S[ia + P2];
        float sb0 = S[ib], sb1 = S[ib + P2];
        float g10 = G1[ig], g11 = G1[ig + P2];
        float g20 = G2[ig], g21 = G2[ig + P2];
        float g30 = G3[ig], g31 = G3[ig + P2];
        float g40 = G4[ig], g41 = G4[ig + P2];
        float na0 = sa0 + DTV * sb0 + cA * (g10 + g20 + g30);
        float na1 = sa1 + DTV * sb1 + cA * (g11 + g21 + g31);
        float nb0 = sb0 + cB * (g10 + 2.f * g20 + 2.f * g30 + g40);
        float nb1 = sb1 + cB * (g11 + 2.f * g21 + 2.f * g31 + g41);
        S[ia] = na0; S[ia + P2] = na1;
        S[ib] = nb0; S[ib + P2] = nb1;
        if (SBF) {
            *(int*)(orow + c0)      = (int)(f2bf(na0) | (f2bf(na1) << 16));
            *(int*)(orow + 96 + c0) = (int)(f2bf(nb0) | (f2bf(nb1) << 16));
        }
    }
}

extern "C" void kernel_launch(void* const* d_in, const int* in_sizes, int n_in,
                              void* d_out, int out_size, void* d_ws, size_t ws_size,
                              hipStream_t stream) {
    (void)in_sizes; (void)n_in; (void)out_size; (void)ws_size;
    const float* x    = (const float*)d_in[0];
    const float* skip = (const float*)d_in[1];
    const float* iv_w = (const float*)d_in[2];
    const float* iv_b = (const float*)d_in[3];
    const float* up_w = (const float*)d_in[4];
    const float* up_b = (const float*)d_in[5];
    const float* f1_w = (const float*)d_in[6];
    const float* f1_b = (const float*)d_in[7];
    const float* f2_w = (const float*)d_in[8];
    const float* f2_b = (const float*)d_in[9];

    float* S = (float*)d_out;                    // B x 192 x P2 fp32 NCHW (state)
    float* ws = (float*)d_ws;
    const size_t NGf = (size_t)BB * CH * P2;     // one G plane (floats)
    float* G1 = ws;
    float* G2 = G1 + NGf;
    float* G3 = G2 + NGf;
    float* G4 = G3 + NGf;
    short* T   = (short*)(G4 + NGf);             // bf16 NHWC [b][P2][192]
    short* U   = T + (size_t)BB * P2 * CS;       // bf16 NHWC [b][P2][96]
    short* SBF = U + (size_t)BB * P2 * CH;       // bf16 NHWC [b][P2][192]
    float* MVS = (float*)(SBF + (size_t)BB * P2 * CS);
    short* IVQ = (short*)(MVS + (size_t)34 * 1536);
    short* F1Q = IVQ + (size_t)9 * NF * NF;
    short* F2Q = F1Q + (size_t)9 * CH * CS;
    short* UPQ = F2Q + (size_t)9 * CH * CH;
    // phase-A aliases (lifetimes end before first G/S write):
    short* YCAT = (short*)G1;                    // [b][P2][384] = G1+G2 exactly
    float* V0   = G3;                            // fp32 NCHW B x 128 x P1
    short* XBF  = (short*)G4;                    // [b][P1][128]

    auto slot = [&](int i) { return MVS + (size_t)i * 1536; };

    // ---- setup ----
    zero_kernel<<<(34 * 1536 + 255) / 256, 256, 0, stream>>>(MVS, 34 * 1536);
    repack_w_kernel<<<(NF * NF * 9 + 255) / 256, 256, 0, stream>>>(iv_w, IVQ, NF, NF);
    repack_w_kernel<<<(CH * CS * 9 + 255) / 256, 256, 0, stream>>>(f1_w, F1Q, CH, CS);
    repack_w_kernel<<<(CH * CH * 9 + 255) / 256, 256, 0, stream>>>(f2_w, F2Q, CH, CH);
    repack_w1_kernel<<<(CS * 384 + 255) / 256, 256, 0, stream>>>(up_w, UPQ, CS * 384);

    // ---- Phase A ----
    meanvar_raw_kernel<<<BB * NF, 256, 0, stream>>>(x, slot(0), P1);
    xcvt_kernel<<<dim3(P1 / 64, BB), 256, 0, stream>>>(x, XBF);
    conv3x3_mfma<4, false, false><<<dim3(W1 / 16, H1 / 8, BB * 2), 256, 0, stream>>>(
        XBF, slot(0), IVQ, iv_b, V0, nullptr, nullptr, NF, NF, H1, W1, NF, 0, 2);
    upsample_kernel<<<dim3(P2 / 64, BB), 256, 0, stream>>>(x, V0, skip, YCAT);
    conv1x1_mfma<<<dim3(P2 / 64, BB), 256, 0, stream>>>(YCAT, UPQ, up_b, S, SBF, slot(1));

    // ---- RK4 ODE ----
    const float h = DTV;
    float* G[4] = {G1, G2, G3, G4};
    int sc = 2;
    float* yslot = slot(1);
    const dim3 egrd(P2 / 64, BB);

    for (int step = 0; step < 4; step++) {
        for (int sub = 0; sub < 4; sub++) {
            const short* Ybf = (sub == 0) ? SBF : T;
            float* uslot = slot(sc++);
            conv3x3_mfma<6, true, true><<<dim3(W2 / 16, H2 / 8, BB), 256, 0, stream>>>(
                Ybf, yslot, F1Q, f1_b, nullptr, U, uslot, CS, CH, H2, W2, CH, 0, 1);
            conv3x3_mfma<6, false, false><<<dim3(W2 / 16, H2 / 8, BB), 256, 0, stream>>>(
                U, uslot, F2Q, f2_b, G[sub], nullptr, nullptr, CH, CH, H2, W2, CH, 0, 1);
            if (sub < 3) {
                float ca1, ca2, cb;
                const float *Gx, *Gp;
                if (sub == 0)      { ca1 = h/2; ca2 = 0.f;     Gx = G1; Gp = G1; cb = h/2; }
                else if (sub == 1) { ca1 = h/2; ca2 = h*h/4;   Gx = G1; Gp = G2; cb = h/2; }
                else               { ca1 = h;   ca2 = h*h/2;   Gx = G2; Gp = G3; cb = h;   }
                combine_kernel<<<egrd, 256, 0, stream>>>(S, Gx, Gp, T, ca1, ca2, cb);
                float* tslot = slot(sc++);
                stats_nhwc_kernel<<<dim3(64, BB), 256, 0, stream>>>(T, tslot);
                yslot = tslot;
            }
        }
        if (step < 3) {
            final_kernel<true><<<egrd, 256, 0, stream>>>(S, G1, G2, G3, G4, SBF);
            float* sslot = slot(sc++);
            stats_nhwc_kernel<<<dim3(64, BB), 256, 0, stream>>>(SBF, sslot);
            yslot = sslot;
        } else {
            final_kernel<false><<<egrd, 256, 0, stream>>>(S, G1, G2, G3, G4, SBF);
        }
    }
}

// Round 6
// 3160.935 us; speedup vs baseline: 1.1203x; 1.1203x over previous
//
#include <hip/hip_runtime.h>
#include <math.h>

#define BB 4
#define NF 128
#define CS 192
#define CH 96
#define H1 64
#define W1 64
#define H2 128
#define W2 128
#define P1 (H1*W1)
#define P2 (H2*W2)
#define EPSV 1e-5f
#define DTV 0.25f

typedef __attribute__((ext_vector_type(8))) short short8;
typedef __attribute__((ext_vector_type(4))) float f32x4;

__device__ __forceinline__ float softplus_f(float x) {
    return fmaxf(x, 0.0f) + log1pf(expf(-fabsf(x)));
}
__device__ __forceinline__ unsigned f2bf(float f) {
    unsigned u = __float_as_uint(f);
    return (u + 0x7FFFu + ((u >> 16) & 1u)) >> 16;   // RNE to bf16
}
__device__ __forceinline__ float bf2f(short s) {
    return __uint_as_float(((unsigned)(unsigned short)s) << 16);
}
__device__ __forceinline__ int packbf(float a, float b) {
    return (int)(f2bf(a) | (f2bf(b) << 16));
}

__global__ __launch_bounds__(256) void zero_kernel(float* __restrict__ p, int n) {
    int i = blockIdx.x * 256 + threadIdx.x;
    if (i < n) p[i] = 0.f;
}

// per-(b,c) raw (sum,sumsq) over HW for fp32 NCHW input x. grid = B*C.
__global__ __launch_bounds__(256) void meanvar_raw_kernel(const float* __restrict__ x,
                                                          float* __restrict__ mv, int HW) {
    int bc = blockIdx.x;
    const float* p = x + (size_t)bc * HW;
    float s = 0.f, s2 = 0.f;
    for (int i = threadIdx.x; i < HW; i += 256) {
        float v = p[i];
        s += v; s2 += v * v;
    }
    __shared__ float sh[512];
    sh[threadIdx.x] = s; sh[256 + threadIdx.x] = s2;
    __syncthreads();
    for (int o = 128; o > 0; o >>= 1) {
        if (threadIdx.x < o) {
            sh[threadIdx.x] += sh[threadIdx.x + o];
            sh[256 + threadIdx.x] += sh[256 + threadIdx.x + o];
        }
        __syncthreads();
    }
    if (threadIdx.x == 0) {
        mv[2 * bc]     = sh[0];
        mv[2 * bc + 1] = sh[256];
    }
}

// raw (sum,sumsq) per (b,c) for bf16 NHWC tensor with C=192. grid (64, B).
__global__ __launch_bounds__(256) void stats_nhwc_kernel(const short* __restrict__ t,
                                                         float* __restrict__ osum) {
    const int tid = threadIdx.x;
    const int k = tid % 24;
    const int ps = tid / 24;
    const int px0 = blockIdx.x * (P2 / 64);
    const int b = blockIdx.y;
    float s1[8], s2[8];
#pragma unroll
    for (int i = 0; i < 8; i++) { s1[i] = 0.f; s2[i] = 0.f; }
    if (tid < 240) {
        for (int px = px0 + ps; px < px0 + P2 / 64; px += 10) {
            short8 v = *(const short8*)(t + ((size_t)b * P2 + px) * 192 + k * 8);
#pragma unroll
            for (int i = 0; i < 8; i++) {
                float f = bf2f(v[i]);
                s1[i] += f; s2[i] += f * f;
            }
        }
    }
    __shared__ float red[240][16];
    if (tid < 240) {
#pragma unroll
        for (int i = 0; i < 8; i++) { red[tid][i] = s1[i]; red[tid][8 + i] = s2[i]; }
    }
    __syncthreads();
    for (int idx = tid; idx < 384; idx += 256) {
        int kk = idx / 16, e = idx % 16;
        float a = 0.f;
#pragma unroll
        for (int p = 0; p < 10; p++) a += red[p * 24 + kk][e];
        int ch = kk * 8 + (e & 7);
        atomicAdd(&osum[((size_t)b * CS + ch) * 2 + (e >> 3)], a);
    }
}

// repack w[co][ci][3][3] fp32 -> wq[tap][co][ci] bf16
__global__ __launch_bounds__(256) void repack_w_kernel(const float* __restrict__ w,
                                                       short* __restrict__ wq,
                                                       int Cout, int Cin) {
    int idx = blockIdx.x * 256 + threadIdx.x;
    int total = Cout * Cin * 9;
    if (idx >= total) return;
    int tap = idx % 9;
    int t = idx / 9;
    int ci = t % Cin, co = t / Cin;
    wq[((size_t)tap * Cout + co) * Cin + ci] = (short)f2bf(w[idx]);
}

__global__ __launch_bounds__(256) void repack_w1_kernel(const float* __restrict__ w,
                                                        short* __restrict__ wq, int n) {
    int i = blockIdx.x * 256 + threadIdx.x;
    if (i < n) wq[i] = (short)f2bf(w[i]);
}

// x fp32 NCHW (B,128,P1) -> bf16 NHWC [b][px][128], LDS transpose. grid (P1/64, B).
__global__ __launch_bounds__(256) void xcvt_kernel(const float* __restrict__ x,
                                                   short* __restrict__ xbf) {
    __shared__ int buf[64 * 68];     // 64 px x 64 int-pairs, pad 68 (272B rows, 16B-align)
    const int tid = threadIdx.x;
    const int px = tid & 63, jj = tid >> 6;
    const int px0 = blockIdx.x * 64;
    const int b = blockIdx.y;
#pragma unroll
    for (int ji = 0; ji < 16; ji++) {
        int j = jj + 4 * ji;         // int-pair index 0..63, wave-uniform
        int c = 2 * j;
        float a = x[((size_t)(b * NF + c)) * P1 + px0 + px];
        float d = x[((size_t)(b * NF + c + 1)) * P1 + px0 + px];
        buf[px * 68 + j] = packbf(a, d);
    }
    __syncthreads();
#pragma unroll
    for (int k = 0; k < 4; k++) {
        int idx = tid + 256 * k;     // 1024 int4s
        int p2 = idx >> 4, w4 = idx & 15;
        int4 v = *(const int4*)&buf[p2 * 68 + w4 * 4];
        *(int4*)(xbf + ((size_t)b * P1 + px0 + p2) * NF + w4 * 8) = v;
    }
}

// 3x3 SAME conv: bf16 NHWC input + instance-norm at staging, register-prefetch
// pipelined staging, MFMA 16x16x32 bf16, softplus+bias epilogue.
// OUTBF=false: fp32 NCHW out. OUTBF=true: bf16 NHWC out via LDS transpose
// (requires NCG=6/outC=96/outCoff=0). grid (W/16, H/8, B*coblk), block 256.
template<int NCG, bool OUTBF, bool SUMS>
__global__ __launch_bounds__(256) void conv3x3_mfma(
    const short* __restrict__ in, const float* __restrict__ mvsums,
    const short* __restrict__ wq, const float* __restrict__ bias,
    float* __restrict__ outf, short* __restrict__ outbf, float* __restrict__ osum,
    int Cin, int CoutT, int H, int W, int outC, int outCoff, int coblk)
{
    // smem: staging tile xt (3600 ints) / (OUTBF) also reused as transpose buf
    constexpr int SMEMI = OUTBF ? 128 * 52 : 3600;
    __shared__ int smem[SMEMI];
    short* xt = (short*)smem;          // 180 px x 40 shorts (80B/px)
    __shared__ float mvm[CS], mvr[CS];
    __shared__ float shs[2 * CH];
    const int tid = threadIdx.x;
    const int wave = tid >> 6, lane = tid & 63;
    const int lx = lane & 15, q = lane >> 4;
    const int x0 = blockIdx.x * 16, y0 = blockIdx.y * 8;
    const int b = blockIdx.z / coblk;
    const int co_base = (blockIdx.z % coblk) * (NCG * 16);
    const int HWp = H * W;
    const short* inb = in + (size_t)b * HWp * Cin;

    const float invHW = 1.0f / (float)HWp;
    for (int c = tid; c < Cin; c += 256) {
        float s  = mvsums[(b * Cin + c) * 2];
        float s2 = mvsums[(b * Cin + c) * 2 + 1];
        float m  = s * invHW;
        float var = fmaxf(s2 * invHW - m * m, 0.f);
        mvm[c] = m;
        mvr[c] = rsqrtf(var + EPSV);
    }
    if (SUMS) for (int c = tid; c < 2 * CH; c += 256) shs[c] = 0.f;
    __syncthreads();

    int jl[3], jg[3], jc[3]; bool jok[3]; int nj = 0;
#pragma unroll
    for (int k = 0; k < 3; k++) {
        int j = tid + 256 * k;
        if (j < 720) {
            int part = j & 3, px = j >> 2;
            int yy = px / 18, xx = px - yy * 18;
            int gy = y0 + yy - 1, gx = x0 + xx - 1;
            bool ok = (gy >= 0 && gy < H && gx >= 0 && gx < W);
            jl[nj] = px * 40 + part * 8;
            jg[nj] = ok ? ((gy * W + gx) * Cin + part * 8) : 0;
            jc[nj] = part * 8;
            jok[nj] = ok;
            nj++;
        }
    }

    f32x4 acc[2][NCG];
#pragma unroll
    for (int rr = 0; rr < 2; rr++)
#pragma unroll
        for (int cg = 0; cg < NCG; cg++) acc[rr][cg] = (f32x4)(0.f);

    const int NIT = Cin >> 5;
    short8 pf[3];
#pragma unroll
    for (int k = 0; k < 3; k++)
        if (k < nj && jok[k]) pf[k] = *(const short8*)(inb + jg[k]);

    for (int it = 0; it < NIT; it++) {
        const int ci0 = it << 5;
        if (it > 0) __syncthreads();
#pragma unroll
        for (int k = 0; k < 3; k++) {
            if (k < nj) {
                int4 wv = make_int4(0, 0, 0, 0);
                if (jok[k]) {
                    int cb = ci0 + jc[k];
                    float4 m0 = *(const float4*)&mvm[cb];
                    float4 m1 = *(const float4*)&mvm[cb + 4];
                    float4 r0 = *(const float4*)&mvr[cb];
                    float4 r1 = *(const float4*)&mvr[cb + 4];
                    short8 v = pf[k];
                    wv.x = packbf((bf2f(v[0]) - m0.x) * r0.x, (bf2f(v[1]) - m0.y) * r0.y);
                    wv.y = packbf((bf2f(v[2]) - m0.z) * r0.z, (bf2f(v[3]) - m0.w) * r0.w);
                    wv.z = packbf((bf2f(v[4]) - m1.x) * r1.x, (bf2f(v[5]) - m1.y) * r1.y);
                    wv.w = packbf((bf2f(v[6]) - m1.z) * r1.z, (bf2f(v[7]) - m1.w) * r1.w);
                }
                *(int4*)(&xt[jl[k]]) = wv;
            }
        }
        __syncthreads();
        if (it + 1 < NIT) {
            const int cn = (it + 1) << 5;
#pragma unroll
            for (int k = 0; k < 3; k++)
                if (k < nj && jok[k]) pf[k] = *(const short8*)(inb + jg[k] + cn);
        }
        const short* wl = wq + (size_t)(co_base + lx) * Cin + ci0 + q * 8;
#pragma unroll
        for (int tap = 0; tap < 9; tap++) {
            const int dy = tap / 3, dx = tap % 3;
            short8 a[NCG];
#pragma unroll
            for (int cg = 0; cg < NCG; cg++)
                a[cg] = *(const short8*)(wl + ((size_t)tap * CoutT + cg * 16) * Cin);
#pragma unroll
            for (int rr = 0; rr < 2; rr++) {
                int row = wave * 2 + rr;
                short8 bfr = *(const short8*)(&xt[((row + dy) * 18 + lx + dx) * 40 + q * 8]);
#pragma unroll
                for (int cg = 0; cg < NCG; cg++)
                    acc[rr][cg] = __builtin_amdgcn_mfma_f32_16x16x32_bf16(
                        a[cg], bfr, acc[rr][cg], 0, 0, 0);
            }
        }
    }

    if (OUTBF) __syncthreads();   // xt reads done; smem reused as transpose buf

    float s1l[NCG][4], s2l[NCG][4];
    if (SUMS) {
#pragma unroll
        for (int cg = 0; cg < NCG; cg++)
#pragma unroll
            for (int r = 0; r < 4; r++) { s1l[cg][r] = 0.f; s2l[cg][r] = 0.f; }
    }
#pragma unroll
    for (int rr = 0; rr < 2; rr++) {
        int y = y0 + wave * 2 + rr;
#pragma unroll
        for (int cg = 0; cg < NCG; cg++) {
            float v[4];
#pragma unroll
            for (int r = 0; r < 4; r++) {
                int co = cg * 16 + q * 4 + r;
                v[r] = softplus_f(acc[rr][cg][r] + bias[co_base + co]);
                if (SUMS) { s1l[cg][r] += v[r]; s2l[cg][r] += v[r] * v[r]; }
            }
            if (OUTBF) {
                int pl = (wave * 2 + rr) * 16 + lx;
                smem[pl * 52 + cg * 8 + q * 2]     = packbf(v[0], v[1]);
                smem[pl * 52 + cg * 8 + q * 2 + 1] = packbf(v[2], v[3]);
            } else {
                float* ob = outf + ((size_t)b * outC + outCoff + co_base) * HWp
                            + y * W + x0 + lx;
#pragma unroll
                for (int r = 0; r < 4; r++)
                    ob[(size_t)(cg * 16 + q * 4 + r) * HWp] = v[r];
            }
        }
    }
    if (OUTBF) {
        __syncthreads();
#pragma unroll
        for (int k = 0; k < 6; k++) {
            int idx = tid + 256 * k;           // 1536 int4s: 128 px x 12 int4
            int pl2 = idx / 12, w4 = idx % 12;
            int4 v = *(const int4*)&smem[pl2 * 52 + w4 * 4];
            int pix = (y0 + (pl2 >> 4)) * W + x0 + (pl2 & 15);
            *(int4*)(outbf + ((size_t)b * HWp + pix) * 96 + w4 * 8) = v;
        }
    }
    if (SUMS) {
#pragma unroll
        for (int cg = 0; cg < NCG; cg++)
#pragma unroll
            for (int r = 0; r < 4; r++) {
                float a1 = s1l[cg][r], a2 = s2l[cg][r];
#pragma unroll
                for (int mask = 1; mask < 16; mask <<= 1) {
                    a1 += __shfl_xor(a1, mask);
                    a2 += __shfl_xor(a2, mask);
                }
                if (lx == 0) {
                    int co = cg * 16 + q * 4 + r;
                    atomicAdd(&shs[2 * co], a1);
                    atomicAdd(&shs[2 * co + 1], a2);
                }
            }
        __syncthreads();
        for (int c = tid; c < 2 * NCG * 16; c += 256)
            atomicAdd(&osum[(size_t)b * 2 * NCG * 16 + c], shs[c]);
    }
}

// bilinear 2x upsample of concat(x,v0) + skip -> YCAT bf16 NHWC [b][px][384],
// LDS transpose for coalesced writes. grid (P2/64, B).
__global__ __launch_bounds__(256) void upsample_kernel(
    const float* __restrict__ x, const float* __restrict__ v0,
    const float* __restrict__ skip, short* __restrict__ ycat)
{
    __shared__ int buf[64 * 196];   // 64 px x 192 int-pairs, pad 196 (784B rows)
    const int tid = threadIdx.x;
    const int px = tid & 63, jj = tid >> 6;
    const int px0 = blockIdx.x * 64;
    const int b = blockIdx.y;
    const int pxg = px0 + px;
    const int ox = pxg & 127, oy = pxg >> 7;
    int my = oy >> 1, mx = ox >> 1;
    int iy0 = (oy & 1) ? my : my - 1;
    float wy0 = (oy & 1) ? 0.75f : 0.25f;
    int ix0 = (ox & 1) ? mx : mx - 1;
    float wx0 = (ox & 1) ? 0.75f : 0.25f;
    int iy1 = min(iy0 + 1, H1 - 1); iy0 = max(iy0, 0);
    int ix1 = min(ix0 + 1, W1 - 1); ix0 = max(ix0, 0);
    float wy1 = 1.f - wy0, wx1 = 1.f - wx0;
    float w00 = wy0 * wx0, w01 = wy0 * wx1, w10 = wy1 * wx0, w11 = wy1 * wx1;
    int o00 = iy0 * W1 + ix0, o01 = iy0 * W1 + ix1;
    int o10 = iy1 * W1 + ix0, o11 = iy1 * W1 + ix1;
#pragma unroll 4
    for (int ji = 0; ji < 48; ji++) {
        int j = jj + 4 * ji;        // wave-uniform int-pair index 0..191
        int c = 2 * j;
        float a, d;
        if (c < 256) {
            const float* s0 = (c < 128) ? x + ((size_t)(b * NF + c)) * P1
                                        : v0 + ((size_t)(b * NF + c - 128)) * P1;
            const float* s1 = s0 + P1;
            a = w00 * s0[o00] + w01 * s0[o01] + w10 * s0[o10] + w11 * s0[o11];
            d = w00 * s1[o00] + w01 * s1[o01] + w10 * s1[o10] + w11 * s1[o11];
        } else {
            const float* sk = skip + ((size_t)(b * NF + c - 256)) * P2 + pxg;
            a = sk[0]; d = sk[P2];
        }
        buf[px * 196 + j] = packbf(a, d);
    }
    __syncthreads();
#pragma unroll
    for (int k = 0; k < 12; k++) {
        int idx = tid + 256 * k;    // 3072 int4s: 64 px x 48 int4
        int p2 = idx / 48, w4 = idx % 48;
        int4 v = *(const int4*)&buf[p2 * 196 + w4 * 4];
        *(int4*)(ycat + ((size_t)b * P2 + px0 + p2) * 384 + w4 * 8) = v;
    }
}

// 1x1 conv 384->192: YCAT bf16 NHWC in, MFMA, softplus; S fp32 NCHW +
// Sbf bf16 NHWC (LDS transpose) + fused channel sums. grid (P2/64, B).
__global__ __launch_bounds__(256) void conv1x1_mfma(
    const short* __restrict__ ycat, const short* __restrict__ wq,
    const float* __restrict__ bias, float* __restrict__ out,
    short* __restrict__ sbf, float* __restrict__ osum)
{
    __shared__ int smem[64 * 100];  // xs staging (first 1280 ints) / transpose buf
    short* xs = (short*)smem;       // 64 px x 40 shorts
    const int tid = threadIdx.x;
    const int wave = tid >> 6, lane = tid & 63;
    const int lx = lane & 15, q = lane >> 4;
    const int p0 = blockIdx.x * 64;
    const int b = blockIdx.y;
    const int spx = tid >> 2, spart = tid & 3;
    const size_t gofs = ((size_t)b * P2 + p0 + spx) * 384 + spart * 8;
    const int ldso = spx * 40 + spart * 8;

    f32x4 acc[3][4];
#pragma unroll
    for (int cg = 0; cg < 3; cg++)
#pragma unroll
        for (int pg = 0; pg < 4; pg++) acc[cg][pg] = (f32x4)(0.f);

    short8 pf = *(const short8*)(ycat + gofs);
    for (int it = 0; it < 12; it++) {
        if (it > 0) __syncthreads();
        *(short8*)(&xs[ldso]) = pf;
        __syncthreads();
        if (it < 11) pf = *(const short8*)(ycat + gofs + (it + 1) * 32);
        const short* wl = wq + (size_t)(wave * 48 + lx) * 384 + it * 32 + q * 8;
        short8 a[3];
#pragma unroll
        for (int cg = 0; cg < 3; cg++)
            a[cg] = *(const short8*)(wl + (size_t)cg * 16 * 384);
#pragma unroll
        for (int pg = 0; pg < 4; pg++) {
            short8 bfr = *(const short8*)(&xs[(pg * 16 + lx) * 40 + q * 8]);
#pragma unroll
            for (int cg = 0; cg < 3; cg++)
                acc[cg][pg] = __builtin_amdgcn_mfma_f32_16x16x32_bf16(
                    a[cg], bfr, acc[cg][pg], 0, 0, 0);
        }
    }
    __syncthreads();   // xs reads done; smem reused as transpose buf

    float s1a[3][4], s2a[3][4];
#pragma unroll
    for (int cg = 0; cg < 3; cg++)
#pragma unroll
        for (int r = 0; r < 4; r++) { s1a[cg][r] = 0.f; s2a[cg][r] = 0.f; }
#pragma unroll
    for (int cg = 0; cg < 3; cg++) {
        int co0 = wave * 48 + cg * 16 + q * 4;
#pragma unroll
        for (int pg = 0; pg < 4; pg++) {
            int pl = pg * 16 + lx;
            float v[4];
#pragma unroll
            for (int r = 0; r < 4; r++) {
                v[r] = softplus_f(acc[cg][pg][r] + bias[co0 + r]);
                out[((size_t)(b * CS + co0 + r)) * P2 + p0 + pl] = v[r];
                s1a[cg][r] += v[r]; s2a[cg][r] += v[r] * v[r];
            }
            smem[pl * 100 + (co0 >> 1)]     = packbf(v[0], v[1]);
            smem[pl * 100 + (co0 >> 1) + 1] = packbf(v[2], v[3]);
        }
    }
    __syncthreads();
#pragma unroll
    for (int k = 0; k < 6; k++) {
        int idx = tid + 256 * k;    // 1536 int4s: 64 px x 24 int4
        int p2 = idx / 24, w4 = idx % 24;
        int4 v = *(const int4*)&smem[p2 * 100 + w4 * 4];
        *(int4*)(sbf + ((size_t)b * P2 + p0 + p2) * 192 + w4 * 8) = v;
    }
#pragma unroll
    for (int cg = 0; cg < 3; cg++)
#pragma unroll
        for (int r = 0; r < 4; r++) {
            float a1 = s1a[cg][r], a2 = s2a[cg][r];
#pragma unroll
            for (int mask = 1; mask < 16; mask <<= 1) {
                a1 += __shfl_xor(a1, mask);
                a2 += __shfl_xor(a2, mask);
            }
            if (lx == 0) {
                int co = wave * 48 + cg * 16 + q * 4 + r;
                atomicAdd(&osum[((size_t)b * CS + co) * 2], a1);
                atomicAdd(&osum[((size_t)b * CS + co) * 2 + 1], a2);
            }
        }
}

// T[a] = S_a + ca1*S_b + ca2*Gx ; T[b] = S_b + cb*Gp ; T bf16 NHWC via LDS transpose.
// grid (P2/64, B).
__global__ __launch_bounds__(256) void combine_kernel(
    const float* __restrict__ S, const float* __restrict__ Gx,
    const float* __restrict__ Gp, short* __restrict__ T,
    float ca1, float ca2, float cb)
{
    __shared__ int buf[64 * 100];
    const int tid = threadIdx.x;
    const int px = tid & 63, jj = tid >> 6;
    const int px0 = blockIdx.x * 64;
    const int b = blockIdx.y;
    const int pxg = px0 + px;
#pragma unroll 3
    for (int ji = 0; ji < 12; ji++) {
        int j = jj + 4 * ji;        // 0..47 = ch-pair over the a-half
        int c = 2 * j;
        size_t ia = ((size_t)(b * CS + c)) * P2 + pxg;
        size_t ib = ia + (size_t)CH * P2;
        size_t ig = ((size_t)(b * CH + c)) * P2 + pxg;
        float sa0 = S[ia], sa1 = S[ia + P2];
        float sb0 = S[ib], sb1 = S[ib + P2];
        float gx0 = Gx[ig], gx1 = Gx[ig + P2];
        float gp0 = Gp[ig], gp1 = Gp[ig + P2];
        buf[px * 100 + j]      = packbf(sa0 + ca1 * sb0 + ca2 * gx0,
                                        sa1 + ca1 * sb1 + ca2 * gx1);
        buf[px * 100 + 48 + j] = packbf(sb0 + cb * gp0, sb1 + cb * gp1);
    }
    __syncthreads();
#pragma unroll
    for (int k = 0; k < 6; k++) {
        int idx = tid + 256 * k;
        int p2 = idx / 24, w4 = idx % 24;
        int4 v = *(const int4*)&buf[p2 * 100 + w4 * 4];
        *(int4*)(T + ((size_t)b * P2 + px0 + p2) * 192 + w4 * 8) = v;
    }
}

// S_a += h*S_b + h^2/6*(g1+g2+g3); S_b += h/6*(g1+2g2+2g3+g4); optional Sbf NHWC.
template<bool SBF>
__global__ __launch_bounds__(256) void final_kernel(
    float* __restrict__ S, const float* __restrict__ G1, const float* __restrict__ G2,
    const float* __restrict__ G3, const float* __restrict__ G4, short* __restrict__ sbf)
{
    __shared__ int buf[SBF ? 64 * 100 : 4];
    const int tid = threadIdx.x;
    const int px = tid & 63, jj = tid >> 6;
    const int px0 = blockIdx.x * 64;
    const int b = blockIdx.y;
    const int pxg = px0 + px;
    const float cA = DTV * DTV / 6.0f, cB = DTV / 6.0f;
#pragma unroll 3
    for (int ji = 0; ji < 12; ji++) {
        int j = jj + 4 * ji;
        int c = 2 * j;
        size_t ia = ((size_t)(b * CS + c)) * P2 + pxg;
        size_t ib = ia + (size_t)CH * P2;
        size_t ig = ((size_t)(b * CH + c)) * P2 + pxg;
        float sa0 = S[ia], sa1 = S[ia + P2];
        float sb0 = S[ib], sb1 = S[ib + P2];
        float g10 = G1[ig], g11 = G1[ig + P2];
        float g20 = G2[ig], g21 = G2[ig + P2];
        float g30 = G3[ig], g31 = G3[ig + P2];
        float g40 = G4[ig], g41 = G4[ig + P2];
        float na0 = sa0 + DTV * sb0 + cA * (g10 + g20 + g30);
        float na1 = sa1 + DTV * sb1 + cA * (g11 + g21 + g31);
        float nb0 = sb0 + cB * (g10 + 2.f * g20 + 2.f * g30 + g40);
        float nb1 = sb1 + cB * (g11 + 2.f * g21 + 2.f * g31 + g41);
        S[ia] = na0; S[ia + P2] = na1;
        S[ib] = nb0; S[ib + P2] = nb1;
        if (SBF) {
            buf[px * 100 + j]      = packbf(na0, na1);
            buf[px * 100 + 48 + j] = packbf(nb0, nb1);
        }
    }
    if (SBF) {
        __syncthreads();
#pragma unroll
        for (int k = 0; k < 6; k++) {
            int idx = tid + 256 * k;
            int p2 = idx / 24, w4 = idx % 24;
            int4 v = *(const int4*)&buf[p2 * 100 + w4 * 4];
            *(int4*)(sbf + ((size_t)b * P2 + px0 + p2) * 192 + w4 * 8) = v;
        }
    }
}

extern "C" void kernel_launch(void* const* d_in, const int* in_sizes, int n_in,
                              void* d_out, int out_size, void* d_ws, size_t ws_size,
                              hipStream_t stream) {
    (void)in_sizes; (void)n_in; (void)out_size; (void)ws_size;
    const float* x    = (const float*)d_in[0];
    const float* skip = (const float*)d_in[1];
    const float* iv_w = (const float*)d_in[2];
    const float* iv_b = (const float*)d_in[3];
    const float* up_w = (const float*)d_in[4];
    const float* up_b = (const float*)d_in[5];
    const float* f1_w = (const float*)d_in[6];
    const float* f1_b = (const float*)d_in[7];
    const float* f2_w = (const float*)d_in[8];
    const float* f2_b = (const float*)d_in[9];

    float* S = (float*)d_out;                    // B x 192 x P2 fp32 NCHW (state)
    float* ws = (float*)d_ws;
    const size_t NGf = (size_t)BB * CH * P2;
    float* G1 = ws;
    float* G2 = G1 + NGf;
    float* G3 = G2 + NGf;
    float* G4 = G3 + NGf;
    short* T   = (short*)(G4 + NGf);             // bf16 NHWC [b][P2][192]
    short* U   = T + (size_t)BB * P2 * CS;       // bf16 NHWC [b][P2][96]
    short* SBF = U + (size_t)BB * P2 * CH;       // bf16 NHWC [b][P2][192]
    float* MVS = (float*)(SBF + (size_t)BB * P2 * CS);
    short* IVQ = (short*)(MVS + (size_t)34 * 1536);
    short* F1Q = IVQ + (size_t)9 * NF * NF;
    short* F2Q = F1Q + (size_t)9 * CH * CS;
    short* UPQ = F2Q + (size_t)9 * CH * CH;
    short* YCAT = (short*)G1;                    // phase-A alias
    float* V0   = G3;                            // phase-A alias
    short* XBF  = (short*)G4;                    // phase-A alias

    auto slot = [&](int i) { return MVS + (size_t)i * 1536; };

    zero_kernel<<<(34 * 1536 + 255) / 256, 256, 0, stream>>>(MVS, 34 * 1536);
    repack_w_kernel<<<(NF * NF * 9 + 255) / 256, 256, 0, stream>>>(iv_w, IVQ, NF, NF);
    repack_w_kernel<<<(CH * CS * 9 + 255) / 256, 256, 0, stream>>>(f1_w, F1Q, CH, CS);
    repack_w_kernel<<<(CH * CH * 9 + 255) / 256, 256, 0, stream>>>(f2_w, F2Q, CH, CH);
    repack_w1_kernel<<<(CS * 384 + 255) / 256, 256, 0, stream>>>(up_w, UPQ, CS * 384);

    // ---- Phase A ----
    meanvar_raw_kernel<<<BB * NF, 256, 0, stream>>>(x, slot(0), P1);
    xcvt_kernel<<<dim3(P1 / 64, BB), 256, 0, stream>>>(x, XBF);
    conv3x3_mfma<4, false, false><<<dim3(W1 / 16, H1 / 8, BB * 2), 256, 0, stream>>>(
        XBF, slot(0), IVQ, iv_b, V0, nullptr, nullptr, NF, NF, H1, W1, NF, 0, 2);
    upsample_kernel<<<dim3(P2 / 64, BB), 256, 0, stream>>>(x, V0, skip, YCAT);
    conv1x1_mfma<<<dim3(P2 / 64, BB), 256, 0, stream>>>(YCAT, UPQ, up_b, S, SBF, slot(1));

    // ---- RK4 ODE ----
    const float h = DTV;
    float* G[4] = {G1, G2, G3, G4};
    int sc = 2;
    float* yslot = slot(1);
    const dim3 egrd(P2 / 64, BB);

    for (int step = 0; step < 4; step++) {
        for (int sub = 0; sub < 4; sub++) {
            const short* Ybf = (sub == 0) ? SBF : T;
            float* uslot = slot(sc++);
            conv3x3_mfma<6, true, true><<<dim3(W2 / 16, H2 / 8, BB), 256, 0, stream>>>(
                Ybf, yslot, F1Q, f1_b, nullptr, U, uslot, CS, CH, H2, W2, CH, 0, 1);
            conv3x3_mfma<6, false, false><<<dim3(W2 / 16, H2 / 8, BB), 256, 0, stream>>>(
                U, uslot, F2Q, f2_b, G[sub], nullptr, nullptr, CH, CH, H2, W2, CH, 0, 1);
            if (sub < 3) {
                float ca1, ca2, cb;
                const float *Gx, *Gp;
                if (sub == 0)      { ca1 = h/2; ca2 = 0.f;     Gx = G1; Gp = G1; cb = h/2; }
                else if (sub == 1) { ca1 = h/2; ca2 = h*h/4;   Gx = G1; Gp = G2; cb = h/2; }
                else               { ca1 = h;   ca2 = h*h/2;   Gx = G2; Gp = G3; cb = h;   }
                combine_kernel<<<egrd, 256, 0, stream>>>(S, Gx, Gp, T, ca1, ca2, cb);
                float* tslot = slot(sc++);
                stats_nhwc_kernel<<<dim3(64, BB), 256, 0, stream>>>(T, tslot);
                yslot = tslot;
            }
        }
        if (step < 3) {
            final_kernel<true><<<egrd, 256, 0, stream>>>(S, G1, G2, G3, G4, SBF);
            float* sslot = slot(sc++);
            stats_nhwc_kernel<<<dim3(64, BB), 256, 0, stream>>>(SBF, sslot);
            yslot = sslot;
        } else {
            final_kernel<false><<<egrd, 256, 0, stream>>>(S, G1, G2, G3, G4, SBF);
        }
    }
}